// Round 1
// baseline (838.028 us; speedup 1.0000x reference)
//
#include <hip/hip_runtime.h>
#include <hip/hip_bf16.h>
#include <hip/hip_fp16.h>

typedef _Float16 half8 __attribute__((ext_vector_type(8)));
typedef _Float16 half4 __attribute__((ext_vector_type(4)));
typedef float f32x4 __attribute__((ext_vector_type(4)));
typedef unsigned int u32;

#define S_LEN 2048
#define HID_DIM 4096
#define N_HEADS 32
#define N_KV 8
#define HEAD_DIM 128
#define SCALE_QK 0.08838834764831845f

// ---------- async global->LDS (16B per lane, wave-uniform LDS base) ----------
__device__ __forceinline__ void async16(void* lds, const void* gptr) {
  __builtin_amdgcn_global_load_lds(
      (const __attribute__((address_space(1))) u32*)gptr,
      (__attribute__((address_space(3))) u32*)lds, 16, 0, 0);
}

// ---------- f32 -> f16 convert (vectorized) ----------
__global__ void conv_f32_f16(const float* __restrict__ src, _Float16* __restrict__ dst, int n4) {
  int i = blockIdx.x * 256 + threadIdx.x;
  if (i < n4) {
    float4 v = ((const float4*)src)[i];
    half4 h;
    h[0] = (_Float16)v.x; h[1] = (_Float16)v.y; h[2] = (_Float16)v.z; h[3] = (_Float16)v.w;
    ((half4*)dst)[i] = h;
  }
}

// ---------- transpose f32 [R][C] -> f16 [C][R] ----------
__global__ void transpose_f32_f16(const float* __restrict__ src, _Float16* __restrict__ dst,
                                  int R, int C) {
  __shared__ _Float16 tile[32][33];
  int bx = blockIdx.x;  // over C
  int by = blockIdx.y;  // over R
  int x = threadIdx.x, y = threadIdx.y;  // (32,8)
#pragma unroll
  for (int k = 0; k < 4; k++)
    tile[y + 8*k][x] = (_Float16)src[(by*32 + y + 8*k) * C + bx*32 + x];
  __syncthreads();
#pragma unroll
  for (int k = 0; k < 4; k++)
    dst[(bx*32 + y + 8*k) * (long)R + by*32 + x] = tile[x][y + 8*k];
}

// ---------- RoPE in place on f16 [S][NHEADS*128] ----------
template <int NHEADS>
__global__ void rope_kernel(_Float16* __restrict__ q, const float* __restrict__ cosb,
                            const float* __restrict__ sinb) {
  int t = blockIdx.x * 256 + threadIdx.x;
  int d = t & 63;
  int h = (t >> 6) % NHEADS;
  int s = t / (64 * NHEADS);
  long base = (long)s * (NHEADS * 128) + h * 128 + d;
  float c = cosb[s * 128 + d];
  float sn = sinb[s * 128 + d];
  float q0 = (float)q[base];
  float q1 = (float)q[base + 64];
  q[base]      = (_Float16)(q0 * c - q1 * sn);
  q[base + 64] = (_Float16)(q1 * c + q0 * sn);
}

// ---------- GEMM: C[M=2048][N] = A[2048][4096] @ Bt[N][4096]^T ----------
// MODE 0: f16 out [M][N]; MODE 1: f16 out transposed [N][M]; MODE 2: f32 out [M][N]
template <int N, int MODE>
__global__ void gemm_kernel(const _Float16* __restrict__ A, const _Float16* __restrict__ Bt,
                            void* __restrict__ Cout) {
  __shared__ _Float16 As[128 * 32];
  __shared__ _Float16 Bs[128 * 32];
  const int K = 4096;
  const int tid = threadIdx.x;
  const int lane = tid & 63;
  const int wid = tid >> 6;
  const int row0 = blockIdx.y * 128;
  const int col0 = blockIdx.x * 128;
  const int wm = wid >> 1, wn = wid & 1;
  const int lr = lane & 15, lg = lane >> 4;

  f32x4 acc[4][4] = {};

  const _Float16* aptr = A  + (long)(row0 + wid*32 + (lane >> 2)) * K + (lane & 3) * 8;
  const _Float16* bptr = Bt + (long)(col0 + wid*32 + (lane >> 2)) * K + (lane & 3) * 8;
  _Float16* alds = As + (wid * 32) * 32;
  _Float16* blds = Bs + (wid * 32) * 32;

  for (int k0 = 0; k0 < K; k0 += 32) {
    async16(alds,            aptr + k0);
    async16(alds + 16 * 32,  aptr + k0 + (long)16 * K);
    async16(blds,            bptr + k0);
    async16(blds + 16 * 32,  bptr + k0 + (long)16 * K);
    __syncthreads();
    half8 a[4], b[4];
#pragma unroll
    for (int mf = 0; mf < 4; mf++)
      a[mf] = *(const half8*)&As[(wm*64 + mf*16 + lr) * 32 + lg * 8];
#pragma unroll
    for (int nf = 0; nf < 4; nf++)
      b[nf] = *(const half8*)&Bs[(wn*64 + nf*16 + lr) * 32 + lg * 8];
#pragma unroll
    for (int mf = 0; mf < 4; mf++)
#pragma unroll
      for (int nf = 0; nf < 4; nf++)
        acc[mf][nf] = __builtin_amdgcn_mfma_f32_16x16x32_f16(a[mf], b[nf], acc[mf][nf], 0, 0, 0);
    __syncthreads();
  }

  // epilogue: C/D frag mapping col = lane&15, row = (lane>>4)*4 + i
#pragma unroll
  for (int mf = 0; mf < 4; mf++) {
#pragma unroll
    for (int nf = 0; nf < 4; nf++) {
      int rbase = row0 + wm*64 + mf*16 + lg*4;
      int col   = col0 + wn*64 + nf*16 + lr;
      if (MODE == 0) {
        _Float16* C = (_Float16*)Cout;
#pragma unroll
        for (int i = 0; i < 4; i++)
          C[(long)(rbase + i) * N + col] = (_Float16)acc[mf][nf][i];
      } else if (MODE == 1) {
        _Float16* C = (_Float16*)Cout;  // [N][2048]
        half4 v;
#pragma unroll
        for (int i = 0; i < 4; i++) v[i] = (_Float16)acc[mf][nf][i];
        *(half4*)&C[(long)col * S_LEN + rbase] = v;
      } else {
        float* C = (float*)Cout;
#pragma unroll
        for (int i = 0; i < 4; i++)
          C[(long)(rbase + i) * N + col] = acc[mf][nf][i];
      }
    }
  }
}

// ---------- fused causal GQA attention ----------
// Q: [S][4096] f16 (roped), K: [S][1024] f16 (roped), Vt: [1024][S] f16
// O: [S][4096] f16.  Block: 256 thr = 4 waves; each wave owns 16 q-rows.
__global__ void attn_kernel(const _Float16* __restrict__ Q, const _Float16* __restrict__ Kb,
                            const _Float16* __restrict__ Vt, _Float16* __restrict__ O) {
  __shared__ _Float16 P_lds[4][16 * 32];
  const int tid = threadIdx.x;
  const int lane = tid & 63;
  const int wid = tid >> 6;
  const int h = blockIdx.y;
  const int g = h >> 2;  // kv head (GROUPS=4)
  const int qbase = blockIdx.x * 64;
  const int qrow0 = qbase + wid * 16;
  const int lr = lane & 15;
  const int lg = lane >> 4;

  // Q A-fragments: lane holds Q[qrow0+lr][t*32 + lg*8 .. +7]
  half8 qf[4];
  const _Float16* qp = Q + (long)(qrow0 + lr) * HID_DIM + h * HEAD_DIM + lg * 8;
#pragma unroll
  for (int t = 0; t < 4; t++) qf[t] = *(const half8*)(qp + t * 32);

  f32x4 oacc[8] = {};
  float mrow[4] = {-1e30f, -1e30f, -1e30f, -1e30f};
  float lrow[4] = {0.f, 0.f, 0.f, 0.f};

  for (int kb = 0; kb <= qrow0 + 15; kb += 32) {
    // S = Q @ K^T for 16 q-rows x 32 kv
    f32x4 sacc[2] = {};
#pragma unroll
    for (int sub = 0; sub < 2; sub++) {
      const _Float16* kp = Kb + (long)(kb + sub * 16 + lr) * (N_KV * HEAD_DIM) + g * HEAD_DIM + lg * 8;
#pragma unroll
      for (int t = 0; t < 4; t++) {
        half8 kf = *(const half8*)(kp + t * 32);
        sacc[sub] = __builtin_amdgcn_mfma_f32_16x16x32_f16(qf[t], kf, sacc[sub], 0, 0, 0);
      }
    }
    // scale + causal mask + online softmax (rows live in 16-lane groups)
    float p[2][4];
    float scl[4];
#pragma unroll
    for (int i = 0; i < 4; i++) {
      int qrow = qrow0 + lg * 4 + i;
      float s0 = sacc[0][i] * SCALE_QK;
      float s1 = sacc[1][i] * SCALE_QK;
      if (kb + lr > qrow) s0 = -1e30f;
      if (kb + 16 + lr > qrow) s1 = -1e30f;
      float m = fmaxf(s0, s1);
      m = fmaxf(m, __shfl_xor(m, 1));
      m = fmaxf(m, __shfl_xor(m, 2));
      m = fmaxf(m, __shfl_xor(m, 4));
      m = fmaxf(m, __shfl_xor(m, 8));
      float mn = fmaxf(mrow[i], m);
      scl[i] = __expf(mrow[i] - mn);
      mrow[i] = mn;
      float p0 = __expf(s0 - mn);
      float p1 = __expf(s1 - mn);
      p[0][i] = p0; p[1][i] = p1;
      float ps = p0 + p1;
      ps += __shfl_xor(ps, 1);
      ps += __shfl_xor(ps, 2);
      ps += __shfl_xor(ps, 4);
      ps += __shfl_xor(ps, 8);
      lrow[i] = lrow[i] * scl[i] + ps;
    }
#pragma unroll
    for (int dt = 0; dt < 8; dt++)
#pragma unroll
      for (int i = 0; i < 4; i++) oacc[dt][i] *= scl[i];

    // transpose P (D-layout -> A-layout) through per-wave LDS
    _Float16* pl = &P_lds[wid][0];
#pragma unroll
    for (int sub = 0; sub < 2; sub++)
#pragma unroll
      for (int i = 0; i < 4; i++)
        pl[(lg * 4 + i) * 32 + sub * 16 + lr] = (_Float16)p[sub][i];
    half8 pa = *(const half8*)&pl[lr * 32 + lg * 8];

    // O += P @ V  (B-frag from Vt rows: contiguous along kv)
#pragma unroll
    for (int dt = 0; dt < 8; dt++) {
      const _Float16* vrow = Vt + (long)(g * HEAD_DIM + dt * 16 + lr) * S_LEN + kb + lg * 8;
      half8 vf = *(const half8*)vrow;
      oacc[dt] = __builtin_amdgcn_mfma_f32_16x16x32_f16(pa, vf, oacc[dt], 0, 0, 0);
    }
  }

  // epilogue: normalize and store f16
#pragma unroll
  for (int dt = 0; dt < 8; dt++) {
#pragma unroll
    for (int i = 0; i < 4; i++) {
      float o = oacc[dt][i] / lrow[i];
      O[(long)(qrow0 + lg * 4 + i) * HID_DIM + h * HEAD_DIM + dt * 16 + lr] = (_Float16)o;
    }
  }
}

extern "C" void kernel_launch(void* const* d_in, const int* in_sizes, int n_in,
                              void* d_out, int out_size, void* d_ws, size_t ws_size,
                              hipStream_t stream) {
  const float* x    = (const float*)d_in[0];
  const float* cosb = (const float*)d_in[1];
  const float* sinb = (const float*)d_in[2];
  // d_in[3] = attn_mask: pure causal, implemented in-kernel
  const float* wq = (const float*)d_in[4];
  const float* wk = (const float*)d_in[5];
  const float* wv = (const float*)d_in[6];
  const float* wo = (const float*)d_in[7];
  float* out = (float*)d_out;

  char* ws = (char*)d_ws;
  _Float16* Xh    = (_Float16*)(ws);                        // 16 MiB, later reused as Oattn
  _Float16* Oattn = Xh;
  _Float16* Qb    = (_Float16*)(ws + (size_t)(16 << 20));   // 16 MiB
  _Float16* Kbuf  = (_Float16*)(ws + (size_t)(32 << 20));   // 4 MiB
  _Float16* Vt    = (_Float16*)(ws + (size_t)(36 << 20));   // 4 MiB
  _Float16* Wt1   = (_Float16*)(ws + (size_t)(40 << 20));   // 32 MiB (wq^T then wo^T)
  _Float16* Wtk   = (_Float16*)(ws + (size_t)(72 << 20));   // 8 MiB (wk^T then wv^T)
  // total 80 MiB

  dim3 b256(256);

  // X -> f16
  conv_f32_f16<<<dim3(S_LEN * HID_DIM / 4 / 256), b256, 0, stream>>>(x, Xh, S_LEN * HID_DIM / 4);

  // Q = X @ Wq
  transpose_f32_f16<<<dim3(4096 / 32, 4096 / 32), dim3(32, 8), 0, stream>>>(wq, Wt1, 4096, 4096);
  gemm_kernel<4096, 0><<<dim3(4096 / 128, S_LEN / 128), b256, 0, stream>>>(Xh, Wt1, Qb);

  // K = X @ Wk
  transpose_f32_f16<<<dim3(1024 / 32, 4096 / 32), dim3(32, 8), 0, stream>>>(wk, Wtk, 4096, 1024);
  gemm_kernel<1024, 0><<<dim3(1024 / 128, S_LEN / 128), b256, 0, stream>>>(Xh, Wtk, Kbuf);

  // V^T = (X @ Wv)^T
  transpose_f32_f16<<<dim3(1024 / 32, 4096 / 32), dim3(32, 8), 0, stream>>>(wv, Wtk, 4096, 1024);
  gemm_kernel<1024, 1><<<dim3(1024 / 128, S_LEN / 128), b256, 0, stream>>>(Xh, Wtk, Vt);

  // RoPE in place
  rope_kernel<N_HEADS><<<dim3(S_LEN * N_HEADS * 64 / 256), b256, 0, stream>>>(Qb, cosb, sinb);
  rope_kernel<N_KV><<<dim3(S_LEN * N_KV * 64 / 256), b256, 0, stream>>>(Kbuf, cosb, sinb);

  // fused causal GQA attention -> Oattn (reuses Xh region)
  attn_kernel<<<dim3(S_LEN / 64, N_HEADS), b256, 0, stream>>>(Qb, Kbuf, Vt, Oattn);

  // out = Oattn @ Wo (f32 out)
  transpose_f32_f16<<<dim3(4096 / 32, 4096 / 32), dim3(32, 8), 0, stream>>>(wo, Wt1, 4096, 4096);
  gemm_kernel<4096, 2><<<dim3(4096 / 128, S_LEN / 128), b256, 0, stream>>>(Oattn, Wt1, out);
}

// Round 2
// 610.445 us; speedup vs baseline: 1.3728x; 1.3728x over previous
//
#include <hip/hip_runtime.h>
#include <hip/hip_bf16.h>
#include <hip/hip_fp16.h>

typedef _Float16 half8 __attribute__((ext_vector_type(8)));
typedef _Float16 half4 __attribute__((ext_vector_type(4)));
typedef float f32x4 __attribute__((ext_vector_type(4)));
typedef unsigned int u32;

#define S_LEN 2048
#define HID_DIM 4096
#define N_HEADS 32
#define N_KV 8
#define HEAD_DIM 128
#define SCALE_QK 0.08838834764831845f

// ---------- async global->LDS (16B per lane, wave-uniform LDS base) ----------
__device__ __forceinline__ void async16(void* lds, const void* gptr) {
  __builtin_amdgcn_global_load_lds(
      (const __attribute__((address_space(1))) u32*)gptr,
      (__attribute__((address_space(3))) u32*)lds, 16, 0, 0);
}

// ---------- f32 -> f16 convert (vectorized) ----------
__global__ void conv_f32_f16(const float* __restrict__ src, _Float16* __restrict__ dst, int n4) {
  int i = blockIdx.x * 256 + threadIdx.x;
  if (i < n4) {
    float4 v = ((const float4*)src)[i];
    half4 h;
    h[0] = (_Float16)v.x; h[1] = (_Float16)v.y; h[2] = (_Float16)v.z; h[3] = (_Float16)v.w;
    ((half4*)dst)[i] = h;
  }
}

// ---------- transpose f32 [R][C] -> f16 [C][R] ----------
__global__ void transpose_f32_f16(const float* __restrict__ src, _Float16* __restrict__ dst,
                                  int R, int C) {
  __shared__ _Float16 tile[32][33];
  int bx = blockIdx.x;  // over C
  int by = blockIdx.y;  // over R
  int x = threadIdx.x, y = threadIdx.y;  // (32,8)
#pragma unroll
  for (int k = 0; k < 4; k++)
    tile[y + 8*k][x] = (_Float16)src[(by*32 + y + 8*k) * C + bx*32 + x];
  __syncthreads();
#pragma unroll
  for (int k = 0; k < 4; k++)
    dst[(bx*32 + y + 8*k) * (long)R + by*32 + x] = tile[x][y + 8*k];
}

// ---------- RoPE in place on f16 [S][NHEADS*128] ----------
template <int NHEADS>
__global__ void rope_kernel(_Float16* __restrict__ q, const float* __restrict__ cosb,
                            const float* __restrict__ sinb) {
  int t = blockIdx.x * 256 + threadIdx.x;
  int d = t & 63;
  int h = (t >> 6) % NHEADS;
  int s = t / (64 * NHEADS);
  long base = (long)s * (NHEADS * 128) + h * 128 + d;
  float c = cosb[s * 128 + d];
  float sn = sinb[s * 128 + d];
  float q0 = (float)q[base];
  float q1 = (float)q[base + 64];
  q[base]      = (_Float16)(q0 * c - q1 * sn);
  q[base + 64] = (_Float16)(q1 * c + q0 * sn);
}

// ---------- GEMM: C[M=2048][N] = A[2048][4096] @ Bt[N][4096]^T ----------
// MODE 0: f16 out [M][N]; MODE 2: f32 out [M][N];
// MODE 3: N=2048 KV-merged: cols <1024 -> K f16 [M][1024] (Cout),
//         cols >=1024 -> V^T f16 [1024][M] (Cout2)
template <int N, int MODE>
__global__ void gemm_kernel(const _Float16* __restrict__ A, const _Float16* __restrict__ Bt,
                            void* __restrict__ Cout, void* __restrict__ Cout2) {
  __shared__ _Float16 As[128 * 32];
  __shared__ _Float16 Bs[128 * 32];
  const int K = 4096;
  const int tid = threadIdx.x;
  const int lane = tid & 63;
  const int wid = tid >> 6;
  const int row0 = blockIdx.y * 128;
  const int col0 = blockIdx.x * 128;
  const int wm = wid >> 1, wn = wid & 1;
  const int lr = lane & 15, lg = lane >> 4;

  f32x4 acc[4][4] = {};

  const _Float16* aptr = A  + (long)(row0 + wid*32 + (lane >> 2)) * K + (lane & 3) * 8;
  const _Float16* bptr = Bt + (long)(col0 + wid*32 + (lane >> 2)) * K + (lane & 3) * 8;
  _Float16* alds = As + (wid * 32) * 32;
  _Float16* blds = Bs + (wid * 32) * 32;

  for (int k0 = 0; k0 < K; k0 += 32) {
    async16(alds,            aptr + k0);
    async16(alds + 16 * 32,  aptr + k0 + (long)16 * K);
    async16(blds,            bptr + k0);
    async16(blds + 16 * 32,  bptr + k0 + (long)16 * K);
    __syncthreads();
    half8 a[4], b[4];
#pragma unroll
    for (int mf = 0; mf < 4; mf++)
      a[mf] = *(const half8*)&As[(wm*64 + mf*16 + lr) * 32 + lg * 8];
#pragma unroll
    for (int nf = 0; nf < 4; nf++)
      b[nf] = *(const half8*)&Bs[(wn*64 + nf*16 + lr) * 32 + lg * 8];
#pragma unroll
    for (int mf = 0; mf < 4; mf++)
#pragma unroll
      for (int nf = 0; nf < 4; nf++)
        acc[mf][nf] = __builtin_amdgcn_mfma_f32_16x16x32_f16(a[mf], b[nf], acc[mf][nf], 0, 0, 0);
    __syncthreads();
  }

  // epilogue: C/D frag mapping col = lane&15, row = (lane>>4)*4 + i
#pragma unroll
  for (int mf = 0; mf < 4; mf++) {
#pragma unroll
    for (int nf = 0; nf < 4; nf++) {
      int rbase = row0 + wm*64 + mf*16 + lg*4;
      int col   = col0 + wn*64 + nf*16 + lr;
      if (MODE == 0) {
        _Float16* C = (_Float16*)Cout;
#pragma unroll
        for (int i = 0; i < 4; i++)
          C[(long)(rbase + i) * N + col] = (_Float16)acc[mf][nf][i];
      } else if (MODE == 2) {
        float* C = (float*)Cout;
#pragma unroll
        for (int i = 0; i < 4; i++)
          C[(long)(rbase + i) * N + col] = acc[mf][nf][i];
      } else {  // MODE 3
        if (col0 < 1024) {
          _Float16* C = (_Float16*)Cout;  // K [S][1024]
#pragma unroll
          for (int i = 0; i < 4; i++)
            C[(long)(rbase + i) * 1024 + col] = (_Float16)acc[mf][nf][i];
        } else {
          _Float16* C = (_Float16*)Cout2;  // V^T [1024][S]
          half4 v;
#pragma unroll
          for (int i = 0; i < 4; i++) v[i] = (_Float16)acc[mf][nf][i];
          *(half4*)&C[(long)(col - 1024) * S_LEN + rbase] = v;
        }
      }
    }
  }
}

// ---------- fused causal GQA attention ----------
// Q: [S][4096] f16 (roped), K: [S][1024] f16 (roped), Vt: [1024][S] f16
// O: [S][4096] f16.  Block: 256 thr = 4 waves; each wave owns 16 q-rows.
// Grid (heads, 32); qblock remapped for uniform per-CU work.
__global__ __launch_bounds__(256, 4) void attn_kernel(
    const _Float16* __restrict__ Q, const _Float16* __restrict__ Kb,
    const _Float16* __restrict__ Vt, _Float16* __restrict__ O) {
  __shared__ _Float16 P_lds[4][16 * 32];
  const int tid = threadIdx.x;
  const int lane = tid & 63;
  const int wid = tid >> 6;
  const int h = blockIdx.x;
  const int g = h >> 2;  // kv head (GROUPS=4)
  const int yb = blockIdx.y;
  const int qb = (yb < 16) ? (2 * yb) : (2 * (31 - yb) + 1);  // balance CU loads
  const int qrow0 = qb * 64 + wid * 16;
  const int lr = lane & 15;
  const int lg = lane >> 4;

  // Q A-fragments: lane holds Q[qrow0+lr][t*32 + lg*8 .. +7]
  half8 qf[4];
  const _Float16* qp = Q + (long)(qrow0 + lr) * HID_DIM + h * HEAD_DIM + lg * 8;
#pragma unroll
  for (int t = 0; t < 4; t++) qf[t] = *(const half8*)(qp + t * 32);

  f32x4 oacc[8] = {};
  float mrow[4] = {-1e30f, -1e30f, -1e30f, -1e30f};
  float lsum[4] = {0.f, 0.f, 0.f, 0.f};

  for (int kb = 0; kb < qrow0 + 16; kb += 32) {
    // K fragments
    half8 kf[8];
    const _Float16* kp = Kb + (long)(kb + lr) * (N_KV * HEAD_DIM) + g * HEAD_DIM + lg * 8;
#pragma unroll
    for (int sub = 0; sub < 2; sub++)
#pragma unroll
      for (int t = 0; t < 4; t++)
        kf[sub * 4 + t] = *(const half8*)(kp + sub * 16 * (N_KV * HEAD_DIM) + t * 32);

    f32x4 sacc[2] = {};
#pragma unroll
    for (int sub = 0; sub < 2; sub++)
#pragma unroll
      for (int t = 0; t < 4; t++)
        sacc[sub] = __builtin_amdgcn_mfma_f32_16x16x32_f16(qf[t], kf[sub * 4 + t], sacc[sub], 0, 0, 0);

    // issue V loads early: latency hides under softmax
    half8 vf[8];
#pragma unroll
    for (int dt = 0; dt < 8; dt++)
      vf[dt] = *(const half8*)(Vt + (long)(g * HEAD_DIM + dt * 16 + lr) * S_LEN + kb + lg * 8);

    // scale + causal mask + lane-local max
    float mx[4];
    bool grow = false;
#pragma unroll
    for (int i = 0; i < 4; i++) {
      int qrow = qrow0 + lg * 4 + i;
      float s0 = sacc[0][i] * SCALE_QK;
      float s1 = sacc[1][i] * SCALE_QK;
      if (kb + lr > qrow) s0 = -1e30f;
      if (kb + 16 + lr > qrow) s1 = -1e30f;
      sacc[0][i] = s0; sacc[1][i] = s1;
      mx[i] = fmaxf(s0, s1);
      grow |= (mx[i] > mrow[i] + 4.0f);
    }
    if (__any((int)grow)) {  // slow path: true row-max reduce + rescale
#pragma unroll
      for (int i = 0; i < 4; i++) {
        float m = mx[i];
        m = fmaxf(m, __shfl_xor(m, 1));
        m = fmaxf(m, __shfl_xor(m, 2));
        m = fmaxf(m, __shfl_xor(m, 4));
        m = fmaxf(m, __shfl_xor(m, 8));
        float mn = fmaxf(mrow[i], m);
        float scl = __expf(mrow[i] - mn);
        mrow[i] = mn;
        lsum[i] *= scl;
#pragma unroll
        for (int dt = 0; dt < 8; dt++) oacc[dt][i] *= scl;
      }
    }
    float p[2][4];
#pragma unroll
    for (int i = 0; i < 4; i++) {
      p[0][i] = __expf(sacc[0][i] - mrow[i]);
      p[1][i] = __expf(sacc[1][i] - mrow[i]);
      lsum[i] += p[0][i] + p[1][i];  // per-lane partial; reduced once at end
    }

    // transpose P (D-layout -> A-layout) through per-wave LDS
    _Float16* pl = &P_lds[wid][0];
#pragma unroll
    for (int sub = 0; sub < 2; sub++)
#pragma unroll
      for (int i = 0; i < 4; i++)
        pl[(lg * 4 + i) * 32 + sub * 16 + lr] = (_Float16)p[sub][i];
    half8 pa = *(const half8*)&pl[lr * 32 + lg * 8];

    // O += P @ V
#pragma unroll
    for (int dt = 0; dt < 8; dt++)
      oacc[dt] = __builtin_amdgcn_mfma_f32_16x16x32_f16(pa, vf[dt], oacc[dt], 0, 0, 0);
  }

  // final row-sum reduce (once), then normalize and store
#pragma unroll
  for (int i = 0; i < 4; i++) {
    float t2 = lsum[i];
    t2 += __shfl_xor(t2, 1);
    t2 += __shfl_xor(t2, 2);
    t2 += __shfl_xor(t2, 4);
    t2 += __shfl_xor(t2, 8);
    lsum[i] = t2;
  }
#pragma unroll
  for (int dt = 0; dt < 8; dt++) {
#pragma unroll
    for (int i = 0; i < 4; i++) {
      float o = oacc[dt][i] / lsum[i];
      O[(long)(qrow0 + lg * 4 + i) * HID_DIM + h * HEAD_DIM + dt * 16 + lr] = (_Float16)o;
    }
  }
}

extern "C" void kernel_launch(void* const* d_in, const int* in_sizes, int n_in,
                              void* d_out, int out_size, void* d_ws, size_t ws_size,
                              hipStream_t stream) {
  const float* x    = (const float*)d_in[0];
  const float* cosb = (const float*)d_in[1];
  const float* sinb = (const float*)d_in[2];
  // d_in[3] = attn_mask: pure causal, implemented in-kernel
  const float* wq = (const float*)d_in[4];
  const float* wk = (const float*)d_in[5];
  const float* wv = (const float*)d_in[6];
  const float* wo = (const float*)d_in[7];
  float* out = (float*)d_out;

  char* ws = (char*)d_ws;
  _Float16* Xh    = (_Float16*)(ws);                        // 16 MiB, later reused as Oattn
  _Float16* Oattn = Xh;
  _Float16* Qb    = (_Float16*)(ws + (size_t)(16 << 20));   // 16 MiB
  _Float16* Kbuf  = (_Float16*)(ws + (size_t)(32 << 20));   // 4 MiB
  _Float16* Vt    = (_Float16*)(ws + (size_t)(36 << 20));   // 4 MiB
  _Float16* Wt1   = (_Float16*)(ws + (size_t)(40 << 20));   // 32 MiB (wq^T, then wk^T|wv^T, then wo^T)
  // total 72 MiB

  dim3 b256(256);

  // X -> f16
  conv_f32_f16<<<dim3(S_LEN * HID_DIM / 4 / 256), b256, 0, stream>>>(x, Xh, S_LEN * HID_DIM / 4);

  // Q = X @ Wq
  transpose_f32_f16<<<dim3(4096 / 32, 4096 / 32), dim3(32, 8), 0, stream>>>(wq, Wt1, 4096, 4096);
  gemm_kernel<4096, 0><<<dim3(4096 / 128, S_LEN / 128), b256, 0, stream>>>(Xh, Wt1, Qb, nullptr);

  // K | V^T merged GEMM (N=2048)
  transpose_f32_f16<<<dim3(1024 / 32, 4096 / 32), dim3(32, 8), 0, stream>>>(wk, Wt1, 4096, 1024);
  transpose_f32_f16<<<dim3(1024 / 32, 4096 / 32), dim3(32, 8), 0, stream>>>(wv, Wt1 + (size_t)1024 * 4096, 4096, 1024);
  gemm_kernel<2048, 3><<<dim3(2048 / 128, S_LEN / 128), b256, 0, stream>>>(Xh, Wt1, Kbuf, Vt);

  // RoPE in place
  rope_kernel<N_HEADS><<<dim3(S_LEN * N_HEADS * 64 / 256), b256, 0, stream>>>(Qb, cosb, sinb);
  rope_kernel<N_KV><<<dim3(S_LEN * N_KV * 64 / 256), b256, 0, stream>>>(Kbuf, cosb, sinb);

  // fused causal GQA attention -> Oattn (reuses Xh region)
  attn_kernel<<<dim3(N_HEADS, 32), b256, 0, stream>>>(Qb, Kbuf, Vt, Oattn);

  // out = Oattn @ Wo (f32 out)
  transpose_f32_f16<<<dim3(4096 / 32, 4096 / 32), dim3(32, 8), 0, stream>>>(wo, Wt1, 4096, 4096);
  gemm_kernel<4096, 2><<<dim3(4096 / 128, S_LEN / 128), b256, 0, stream>>>(Oattn, Wt1, out, nullptr);
}

// Round 3
// 464.958 us; speedup vs baseline: 1.8024x; 1.3129x over previous
//
#include <hip/hip_runtime.h>
#include <hip/hip_bf16.h>
#include <hip/hip_fp16.h>

typedef _Float16 half8 __attribute__((ext_vector_type(8)));
typedef _Float16 half4 __attribute__((ext_vector_type(4)));
typedef float f32x4 __attribute__((ext_vector_type(4)));
typedef unsigned int u32;

#define S_LEN 2048
#define HID_DIM 4096
#define N_HEADS 32
#define N_KV 8
#define HEAD_DIM 128
#define SCALE_QK 0.08838834764831845f

// ---------- async global->LDS (16B per lane, wave-uniform LDS base) ----------
__device__ __forceinline__ void async16(void* lds, const void* gptr) {
  __builtin_amdgcn_global_load_lds(
      (const __attribute__((address_space(1))) u32*)gptr,
      (__attribute__((address_space(3))) u32*)lds, 16, 0, 0);
}

// ---------- f32 -> f16 convert (vectorized) ----------
__global__ void conv_f32_f16(const float* __restrict__ src, _Float16* __restrict__ dst, int n4) {
  int i = blockIdx.x * 256 + threadIdx.x;
  if (i < n4) {
    float4 v = ((const float4*)src)[i];
    half4 h;
    h[0] = (_Float16)v.x; h[1] = (_Float16)v.y; h[2] = (_Float16)v.z; h[3] = (_Float16)v.w;
    ((half4*)dst)[i] = h;
  }
}

// ---------- transpose f32 [R][C] -> f16 [C][R] ----------
__global__ void transpose_f32_f16(const float* __restrict__ src, _Float16* __restrict__ dst,
                                  int R, int C) {
  __shared__ _Float16 tile[32][33];
  int bx = blockIdx.x;  // over C
  int by = blockIdx.y;  // over R
  int x = threadIdx.x, y = threadIdx.y;  // (32,8)
#pragma unroll
  for (int k = 0; k < 4; k++)
    tile[y + 8*k][x] = (_Float16)src[(by*32 + y + 8*k) * C + bx*32 + x];
  __syncthreads();
#pragma unroll
  for (int k = 0; k < 4; k++)
    dst[(bx*32 + y + 8*k) * (long)R + by*32 + x] = tile[x][y + 8*k];
}

// ---------- RoPE + retile: linear [S][NHEADS*128] -> tiled [h][s/16][d/32][s%16][(d%32)/8][8] ----------
template <int NHEADS>
__global__ void rope_tile_kernel(const _Float16* __restrict__ src, _Float16* __restrict__ dst,
                                 const float* __restrict__ cosb, const float* __restrict__ sinb) {
  int idx = blockIdx.x * 256 + threadIdx.x;  // S*NHEADS*16
  int d8 = idx & 15;
  int h = (idx >> 4) % NHEADS;
  int s = idx / (16 * NHEADS);
  int d0 = d8 * 8;
  const _Float16* row = src + (long)s * (NHEADS * 128) + h * 128;
  half8 a = *(const half8*)(row + d0);
  half8 b = *(const half8*)(row + (d0 ^ 64));
  float sign = (d0 < 64) ? -1.f : 1.f;
  float4 c0 = *(const float4*)(cosb + s * 128 + d0);
  float4 c1 = *(const float4*)(cosb + s * 128 + d0 + 4);
  float4 sn0 = *(const float4*)(sinb + s * 128 + d0);
  float4 sn1 = *(const float4*)(sinb + s * 128 + d0 + 4);
  float cc[8] = {c0.x, c0.y, c0.z, c0.w, c1.x, c1.y, c1.z, c1.w};
  float ss[8] = {sn0.x, sn0.y, sn0.z, sn0.w, sn1.x, sn1.y, sn1.z, sn1.w};
  half8 o;
#pragma unroll
  for (int j = 0; j < 8; j++)
    o[j] = (_Float16)((float)a[j] * cc[j] + sign * (float)b[j] * ss[j]);
  int qt = s >> 4, t = d0 >> 5, lr = s & 15, lg = (d0 >> 3) & 3;
  long off = ((((long)h * 128 + qt) * 4 + t) * 16 + lr) * 32 + lg * 8;
  *(half8*)(dst + off) = o;
}

// ---------- GEMM: C[M=2048][N] = A[2048][4096] @ Bt[N][4096]^T ----------
// MODE 0: f16 out [M][N]; MODE 2: f32 out [M][N];
// MODE 3: N=2048 KV-merged: cols <1024 -> K f16 [M][1024] (Cout),
//         cols >=1024 -> V tiled [g][kv/32][dt][lr][lg][8] (Cout2)
template <int N, int MODE>
__global__ void gemm_kernel(const _Float16* __restrict__ A, const _Float16* __restrict__ Bt,
                            void* __restrict__ Cout, void* __restrict__ Cout2) {
  __shared__ _Float16 As[128 * 32];
  __shared__ _Float16 Bs[128 * 32];
  const int K = 4096;
  const int tid = threadIdx.x;
  const int lane = tid & 63;
  const int wid = tid >> 6;
  const int row0 = blockIdx.y * 128;
  const int col0 = blockIdx.x * 128;
  const int wm = wid >> 1, wn = wid & 1;
  const int lr = lane & 15, lg = lane >> 4;

  f32x4 acc[4][4] = {};

  const _Float16* aptr = A  + (long)(row0 + wid*32 + (lane >> 2)) * K + (lane & 3) * 8;
  const _Float16* bptr = Bt + (long)(col0 + wid*32 + (lane >> 2)) * K + (lane & 3) * 8;
  _Float16* alds = As + (wid * 32) * 32;
  _Float16* blds = Bs + (wid * 32) * 32;

  for (int k0 = 0; k0 < K; k0 += 32) {
    async16(alds,            aptr + k0);
    async16(alds + 16 * 32,  aptr + k0 + (long)16 * K);
    async16(blds,            bptr + k0);
    async16(blds + 16 * 32,  bptr + k0 + (long)16 * K);
    __syncthreads();
    half8 a[4], b[4];
#pragma unroll
    for (int mf = 0; mf < 4; mf++)
      a[mf] = *(const half8*)&As[(wm*64 + mf*16 + lr) * 32 + lg * 8];
#pragma unroll
    for (int nf = 0; nf < 4; nf++)
      b[nf] = *(const half8*)&Bs[(wn*64 + nf*16 + lr) * 32 + lg * 8];
#pragma unroll
    for (int mf = 0; mf < 4; mf++)
#pragma unroll
      for (int nf = 0; nf < 4; nf++)
        acc[mf][nf] = __builtin_amdgcn_mfma_f32_16x16x32_f16(a[mf], b[nf], acc[mf][nf], 0, 0, 0);
    __syncthreads();
  }

  // epilogue: C/D frag mapping col = lane&15, row = (lane>>4)*4 + i
#pragma unroll
  for (int mf = 0; mf < 4; mf++) {
#pragma unroll
    for (int nf = 0; nf < 4; nf++) {
      int rbase = row0 + wm*64 + mf*16 + lg*4;
      int col   = col0 + wn*64 + nf*16 + lr;
      if (MODE == 0) {
        _Float16* C = (_Float16*)Cout;
#pragma unroll
        for (int i = 0; i < 4; i++)
          C[(long)(rbase + i) * N + col] = (_Float16)acc[mf][nf][i];
      } else if (MODE == 2) {
        float* C = (float*)Cout;
#pragma unroll
        for (int i = 0; i < 4; i++)
          C[(long)(rbase + i) * N + col] = acc[mf][nf][i];
      } else {  // MODE 3
        if (col0 < 1024) {
          _Float16* C = (_Float16*)Cout;  // K linear [S][1024]
#pragma unroll
          for (int i = 0; i < 4; i++)
            C[(long)(rbase + i) * 1024 + col] = (_Float16)acc[mf][nf][i];
        } else {
          // V tiled: element (d, kv) -> [g][kv/32][d%128/16][d%16][(kv%32)/8][kv%8]
          _Float16* C = (_Float16*)Cout2;
          int dglob = col - 1024;
          int gq = dglob >> 7;
          int d = dglob & 127;
          int dt = d >> 4, lrr = d & 15;
          int kvb = rbase >> 5, lgv = (rbase & 31) >> 3, j = rbase & 7;
          half4 v;
#pragma unroll
          for (int i = 0; i < 4; i++) v[i] = (_Float16)acc[mf][nf][i];
          long off = ((((long)gq * 64 + kvb) * 8 + dt) * 16 + lrr) * 32 + lgv * 8 + j;
          *(half4*)&C[off] = v;
        }
      }
    }
  }
}

// ---------- fused causal GQA attention, tiled operands ----------
// Qt: [32][128][4][16][4][8], Kt: [8][128][4][16][4][8], Vt: [8][64][8][16][4][8]
// O: [S][4096] f16 linear.  1 wave per block, 16 q-rows per wave.
// bid%8 = kv-head -> all blocks sharing K/V land on one XCD (L2 residency).
__global__ __launch_bounds__(64, 3) void attn_kernel(
    const _Float16* __restrict__ Qt, const _Float16* __restrict__ Kt,
    const _Float16* __restrict__ Vt, _Float16* __restrict__ O) {
  __shared__ _Float16 P_lds[16 * 32];
  const int lane = threadIdx.x;
  const int bid = blockIdx.x;        // 4096
  const int g = bid & 7;             // kv head == XCD
  const int rest = bid >> 3;         // 0..511
  const int h = g * 4 + (rest & 3);  // q head
  const int qidx = rest >> 2;        // 0..127
  const int qt16 = (qidx < 64) ? (2 * qidx) : (2 * (127 - qidx) + 1);  // balance
  const int qrow0 = qt16 * 16;
  const int lr = lane & 15;
  const int lg = lane >> 4;

  // Q fragments: contiguous 1KB per load
  half8 qf[4];
  {
    const _Float16* qp = Qt + (((long)h * 128 + qt16) * 4 * 16 + lr) * 32 + lg * 8;
#pragma unroll
    for (int t = 0; t < 4; t++) qf[t] = *(const half8*)(qp + t * 512);
  }

  f32x4 oacc[8] = {};
  float mrow[4] = {-1e30f, -1e30f, -1e30f, -1e30f};
  float lsum[4] = {0.f, 0.f, 0.f, 0.f};

  const int kend = qrow0 + 16;
  const _Float16* kgbase = Kt + (long)g * 128 * 2048 + lr * 32 + lg * 8;
  const _Float16* vgbase = Vt + (long)g * 64 * 4096 + lr * 32 + lg * 8;

  for (int kb = 0; kb < kend; kb += 32) {
    // K fragments: contiguous 1KB per load, sequential
    const _Float16* kb0 = kgbase + (kb >> 4) * 2048;
    half8 kf[8];
#pragma unroll
    for (int s = 0; s < 2; s++)
#pragma unroll
      for (int t = 0; t < 4; t++)
        kf[s * 4 + t] = *(const half8*)(kb0 + s * 2048 + t * 512);

    // V fragments issued early: contiguous 8KB block
    const _Float16* vb0 = vgbase + (long)(kb >> 5) * 4096;
    half8 vf[8];
#pragma unroll
    for (int dt = 0; dt < 8; dt++)
      vf[dt] = *(const half8*)(vb0 + dt * 512);

    f32x4 sacc[2] = {};
#pragma unroll
    for (int s = 0; s < 2; s++)
#pragma unroll
      for (int t = 0; t < 4; t++)
        sacc[s] = __builtin_amdgcn_mfma_f32_16x16x32_f16(qf[t], kf[s * 4 + t], sacc[s], 0, 0, 0);

    // scale + causal mask + lane-local max (deferred-max)
    float mx[4];
    bool grow = false;
#pragma unroll
    for (int i = 0; i < 4; i++) {
      int qrow = qrow0 + lg * 4 + i;
      float s0 = sacc[0][i] * SCALE_QK;
      float s1 = sacc[1][i] * SCALE_QK;
      if (kb + lr > qrow) s0 = -1e30f;
      if (kb + 16 + lr > qrow) s1 = -1e30f;
      sacc[0][i] = s0; sacc[1][i] = s1;
      mx[i] = fmaxf(s0, s1);
      grow |= (mx[i] > mrow[i] + 4.0f);
    }
    if (__any((int)grow)) {  // slow path: true row-max reduce + rescale
#pragma unroll
      for (int i = 0; i < 4; i++) {
        float m = mx[i];
        m = fmaxf(m, __shfl_xor(m, 1));
        m = fmaxf(m, __shfl_xor(m, 2));
        m = fmaxf(m, __shfl_xor(m, 4));
        m = fmaxf(m, __shfl_xor(m, 8));
        float mn = fmaxf(mrow[i], m);
        float scl = __expf(mrow[i] - mn);
        mrow[i] = mn;
        lsum[i] *= scl;
#pragma unroll
        for (int dt = 0; dt < 8; dt++) oacc[dt][i] *= scl;
      }
    }
    float p[2][4];
#pragma unroll
    for (int i = 0; i < 4; i++) {
      p[0][i] = __expf(sacc[0][i] - mrow[i]);
      p[1][i] = __expf(sacc[1][i] - mrow[i]);
      lsum[i] += p[0][i] + p[1][i];
    }

    // transpose P (D-layout -> A-layout) through LDS (per-wave buffer)
#pragma unroll
    for (int sub = 0; sub < 2; sub++)
#pragma unroll
      for (int i = 0; i < 4; i++)
        P_lds[(lg * 4 + i) * 32 + sub * 16 + lr] = (_Float16)p[sub][i];
    half8 pa = *(const half8*)&P_lds[lr * 32 + lg * 8];

    // O += P @ V
#pragma unroll
    for (int dt = 0; dt < 8; dt++)
      oacc[dt] = __builtin_amdgcn_mfma_f32_16x16x32_f16(pa, vf[dt], oacc[dt], 0, 0, 0);
  }

  // final row-sum reduce, normalize, store
#pragma unroll
  for (int i = 0; i < 4; i++) {
    float t2 = lsum[i];
    t2 += __shfl_xor(t2, 1);
    t2 += __shfl_xor(t2, 2);
    t2 += __shfl_xor(t2, 4);
    t2 += __shfl_xor(t2, 8);
    lsum[i] = t2;
  }
#pragma unroll
  for (int dt = 0; dt < 8; dt++) {
#pragma unroll
    for (int i = 0; i < 4; i++) {
      float o = oacc[dt][i] / lsum[i];
      O[(long)(qrow0 + lg * 4 + i) * HID_DIM + h * HEAD_DIM + dt * 16 + lr] = (_Float16)o;
    }
  }
}

extern "C" void kernel_launch(void* const* d_in, const int* in_sizes, int n_in,
                              void* d_out, int out_size, void* d_ws, size_t ws_size,
                              hipStream_t stream) {
  const float* x    = (const float*)d_in[0];
  const float* cosb = (const float*)d_in[1];
  const float* sinb = (const float*)d_in[2];
  // d_in[3] = attn_mask: pure causal, implemented in-kernel
  const float* wq = (const float*)d_in[4];
  const float* wk = (const float*)d_in[5];
  const float* wv = (const float*)d_in[6];
  const float* wo = (const float*)d_in[7];
  float* out = (float*)d_out;

  char* ws = (char*)d_ws;
  _Float16* Xh     = (_Float16*)(ws);                       // 0..16M  (X f16; later Qtiled)
  _Float16* Qtiled = Xh;
  _Float16* Qb     = (_Float16*)(ws + (size_t)(16 << 20));  // 16..32M (Q linear; later Oattn)
  _Float16* Oattn  = Qb;
  _Float16* Kbuf   = (_Float16*)(ws + (size_t)(32 << 20));  // 32..36M (K linear)
  _Float16* Vt2    = (_Float16*)(ws + (size_t)(36 << 20));  // 36..40M (V tiled)
  _Float16* Wt1    = (_Float16*)(ws + (size_t)(40 << 20));  // 40..72M (weightsT)
  _Float16* Kt     = (_Float16*)(ws + (size_t)(72 << 20));  // 72..76M (K tiled)
  // total 76 MiB

  dim3 b256(256);

  // X -> f16
  conv_f32_f16<<<dim3(S_LEN * HID_DIM / 4 / 256), b256, 0, stream>>>(x, Xh, S_LEN * HID_DIM / 4);

  // Q = X @ Wq (linear)
  transpose_f32_f16<<<dim3(4096 / 32, 4096 / 32), dim3(32, 8), 0, stream>>>(wq, Wt1, 4096, 4096);
  gemm_kernel<4096, 0><<<dim3(4096 / 128, S_LEN / 128), b256, 0, stream>>>(Xh, Wt1, Qb, nullptr);

  // K (linear) | V (tiled) merged GEMM
  transpose_f32_f16<<<dim3(1024 / 32, 4096 / 32), dim3(32, 8), 0, stream>>>(wk, Wt1, 4096, 1024);
  transpose_f32_f16<<<dim3(1024 / 32, 4096 / 32), dim3(32, 8), 0, stream>>>(wv, Wt1 + (size_t)1024 * 4096, 4096, 1024);
  gemm_kernel<2048, 3><<<dim3(2048 / 128, S_LEN / 128), b256, 0, stream>>>(Xh, Wt1, Kbuf, Vt2);

  // RoPE + retile (Q: Qb -> Qtiled, K: Kbuf -> Kt)
  rope_tile_kernel<N_HEADS><<<dim3(S_LEN * N_HEADS * 16 / 256), b256, 0, stream>>>(Qb, Qtiled, cosb, sinb);
  rope_tile_kernel<N_KV><<<dim3(S_LEN * N_KV * 16 / 256), b256, 0, stream>>>(Kbuf, Kt, cosb, sinb);

  // fused causal GQA attention -> Oattn
  attn_kernel<<<dim3(4096), dim3(64), 0, stream>>>(Qtiled, Kt, Vt2, Oattn);

  // out = Oattn @ Wo (f32 out)
  transpose_f32_f16<<<dim3(4096 / 32, 4096 / 32), dim3(32, 8), 0, stream>>>(wo, Wt1, 4096, 4096);
  gemm_kernel<4096, 2><<<dim3(4096 / 128, S_LEN / 128), b256, 0, stream>>>(Oattn, Wt1, out, nullptr);
}

// Round 4
// 395.838 us; speedup vs baseline: 2.1171x; 1.1746x over previous
//
#include <hip/hip_runtime.h>
#include <hip/hip_bf16.h>
#include <hip/hip_fp16.h>

typedef _Float16 half8 __attribute__((ext_vector_type(8)));
typedef _Float16 half4 __attribute__((ext_vector_type(4)));
typedef float f32x4 __attribute__((ext_vector_type(4)));
typedef unsigned int u32;

#define S_LEN 2048
#define HID_DIM 4096
#define N_HEADS 32
#define N_KV 8
#define HEAD_DIM 128
#define SCALE_QK 0.08838834764831845f

// ---------- async global->LDS (16B per lane, wave-uniform LDS base) ----------
__device__ __forceinline__ void async16(void* lds, const void* gptr) {
  __builtin_amdgcn_global_load_lds(
      (const __attribute__((address_space(1))) u32*)gptr,
      (__attribute__((address_space(3))) u32*)lds, 16, 0, 0);
}

// ---------- f32 -> f16 convert (vectorized) ----------
__global__ void conv_f32_f16(const float* __restrict__ src, _Float16* __restrict__ dst, int n4) {
  int i = blockIdx.x * 256 + threadIdx.x;
  if (i < n4) {
    float4 v = ((const float4*)src)[i];
    half4 h;
    h[0] = (_Float16)v.x; h[1] = (_Float16)v.y; h[2] = (_Float16)v.z; h[3] = (_Float16)v.w;
    ((half4*)dst)[i] = h;
  }
}

// ---------- transpose f32 [R][C] -> f16 [C][R] ----------
__global__ void transpose_f32_f16(const float* __restrict__ src, _Float16* __restrict__ dst,
                                  int R, int C) {
  __shared__ _Float16 tile[32][33];
  int bx = blockIdx.x;  // over C
  int by = blockIdx.y;  // over R
  int x = threadIdx.x, y = threadIdx.y;  // (32,8)
#pragma unroll
  for (int k = 0; k < 4; k++)
    tile[y + 8*k][x] = (_Float16)src[(by*32 + y + 8*k) * C + bx*32 + x];
  __syncthreads();
#pragma unroll
  for (int k = 0; k < 4; k++)
    dst[(bx*32 + y + 8*k) * (long)R + by*32 + x] = tile[x][y + 8*k];
}

// ---------- RoPE + retile: linear [S][NHEADS*128] -> frag-tiled ----------
// element (h,s,d) -> chunk = (h*128 + s/16)*4 + d/32, slot = ((d/8)%4)*16 + s%16, elem = d%8
template <int NHEADS>
__global__ void rope_tile_kernel(const _Float16* __restrict__ src, _Float16* __restrict__ dst,
                                 const float* __restrict__ cosb, const float* __restrict__ sinb) {
  int idx = blockIdx.x * 256 + threadIdx.x;  // S*NHEADS*16
  int d8 = idx & 15;
  int h = (idx >> 4) % NHEADS;
  int s = idx / (16 * NHEADS);
  int d0 = d8 * 8;
  const _Float16* row = src + (long)s * (NHEADS * 128) + h * 128;
  half8 a = *(const half8*)(row + d0);
  half8 b = *(const half8*)(row + (d0 ^ 64));
  float sign = (d0 < 64) ? -1.f : 1.f;
  float4 c0 = *(const float4*)(cosb + s * 128 + d0);
  float4 c1 = *(const float4*)(cosb + s * 128 + d0 + 4);
  float4 sn0 = *(const float4*)(sinb + s * 128 + d0);
  float4 sn1 = *(const float4*)(sinb + s * 128 + d0 + 4);
  float cc[8] = {c0.x, c0.y, c0.z, c0.w, c1.x, c1.y, c1.z, c1.w};
  float ss[8] = {sn0.x, sn0.y, sn0.z, sn0.w, sn1.x, sn1.y, sn1.z, sn1.w};
  half8 o;
#pragma unroll
  for (int j = 0; j < 8; j++)
    o[j] = (_Float16)((float)a[j] * cc[j] + sign * (float)b[j] * ss[j]);
  int qt = s >> 4, t = d0 >> 5, lr = s & 15, lg = (d0 >> 3) & 3;
  long off = (((long)(h * 128 + qt) * 4 + t) * 64 + lg * 16 + lr) * 8;
  *(half8*)(dst + off) = o;
}

// ---------- GEMM: C[M=2048][N] = A[2048][4096] @ Bt[N][4096]^T ----------
// MODE 0: f16 out [M][N]; MODE 2: f32 out [M][N];
// MODE 3: N=2048 KV-merged: cols <1024 -> K f16 [M][1024] (Cout),
//         cols >=1024 -> V frag-tiled (Cout2)
template <int N, int MODE>
__global__ void gemm_kernel(const _Float16* __restrict__ A, const _Float16* __restrict__ Bt,
                            void* __restrict__ Cout, void* __restrict__ Cout2) {
  __shared__ _Float16 As[128 * 32];
  __shared__ _Float16 Bs[128 * 32];
  const int K = 4096;
  const int tid = threadIdx.x;
  const int lane = tid & 63;
  const int wid = tid >> 6;
  const int row0 = blockIdx.y * 128;
  const int col0 = blockIdx.x * 128;
  const int wm = wid >> 1, wn = wid & 1;
  const int lr = lane & 15, lg = lane >> 4;

  f32x4 acc[4][4] = {};

  const _Float16* aptr = A  + (long)(row0 + wid*32 + (lane >> 2)) * K + (lane & 3) * 8;
  const _Float16* bptr = Bt + (long)(col0 + wid*32 + (lane >> 2)) * K + (lane & 3) * 8;
  _Float16* alds = As + (wid * 32) * 32;
  _Float16* blds = Bs + (wid * 32) * 32;

  for (int k0 = 0; k0 < K; k0 += 32) {
    async16(alds,            aptr + k0);
    async16(alds + 16 * 32,  aptr + k0 + (long)16 * K);
    async16(blds,            bptr + k0);
    async16(blds + 16 * 32,  bptr + k0 + (long)16 * K);
    __syncthreads();
    half8 a[4], b[4];
#pragma unroll
    for (int mf = 0; mf < 4; mf++)
      a[mf] = *(const half8*)&As[(wm*64 + mf*16 + lr) * 32 + lg * 8];
#pragma unroll
    for (int nf = 0; nf < 4; nf++)
      b[nf] = *(const half8*)&Bs[(wn*64 + nf*16 + lr) * 32 + lg * 8];
#pragma unroll
    for (int mf = 0; mf < 4; mf++)
#pragma unroll
      for (int nf = 0; nf < 4; nf++)
        acc[mf][nf] = __builtin_amdgcn_mfma_f32_16x16x32_f16(a[mf], b[nf], acc[mf][nf], 0, 0, 0);
    __syncthreads();
  }

  // epilogue: C/D frag mapping col = lane&15, row = (lane>>4)*4 + i
#pragma unroll
  for (int mf = 0; mf < 4; mf++) {
#pragma unroll
    for (int nf = 0; nf < 4; nf++) {
      int rbase = row0 + wm*64 + mf*16 + lg*4;
      int col   = col0 + wn*64 + nf*16 + lr;
      if (MODE == 0) {
        _Float16* C = (_Float16*)Cout;
#pragma unroll
        for (int i = 0; i < 4; i++)
          C[(long)(rbase + i) * N + col] = (_Float16)acc[mf][nf][i];
      } else if (MODE == 2) {
        float* C = (float*)Cout;
#pragma unroll
        for (int i = 0; i < 4; i++)
          C[(long)(rbase + i) * N + col] = acc[mf][nf][i];
      } else {  // MODE 3
        if (col0 < 1024) {
          _Float16* C = (_Float16*)Cout;  // K linear [S][1024]
#pragma unroll
          for (int i = 0; i < 4; i++)
            C[(long)(rbase + i) * 1024 + col] = (_Float16)acc[mf][nf][i];
        } else {
          // V frag-tiled: (d_global, kv) -> chunk=(gq*64+kv/32)*8 + (d%128)/16,
          //               slot = ((kv/8)%4)*16 + d%16, elem = kv%8
          _Float16* C = (_Float16*)Cout2;
          int dglob = col - 1024;
          int gq = dglob >> 7;
          int d = dglob & 127;
          int dt = d >> 4, lrr = d & 15;
          int kvb = rbase >> 5, lgv = (rbase >> 3) & 3, j = rbase & 7;
          half4 v;
#pragma unroll
          for (int i = 0; i < 4; i++) v[i] = (_Float16)acc[mf][nf][i];
          long off = ((long)(gq * 64 + kvb) * 8 + dt) * 512 + (lgv * 16 + lrr) * 8 + j;
          *(half4*)&C[off] = v;
        }
      }
    }
  }
}

// ---------- fused causal GQA attention, LDS-shared K/V ----------
// Qt: frag-tiled [32*128 chunks*4][64][8], Kt: same for 8 kv-heads,
// Vt: frag-tiled [8*64 tiles*8][64][8].  O: [S][4096] f16 linear.
// Block: 256 thr = 4 waves = the 4 q-heads of one kv-head, all at the SAME
// q-tile -> identical kv range -> K/V staged once in LDS, shared 4 ways.
// Double-buffered staging: stage(t+1) issued before compute(t); one
// __syncthreads per tile (its vmcnt(0) drain IS the pipeline wait).
__global__ __launch_bounds__(256, 3) void attn_kernel(
    const _Float16* __restrict__ Qt, const _Float16* __restrict__ Kt,
    const _Float16* __restrict__ Vt, _Float16* __restrict__ O) {
  __shared__ _Float16 Klds[2][4096];   // 8KB per buffer
  __shared__ _Float16 Vlds[2][4096];
  __shared__ _Float16 P_lds[4][512];
  const int tid = threadIdx.x;
  const int lane = tid & 63;
  const int wid = tid >> 6;
  const int bid = blockIdx.x;        // 1024
  const int g = bid & 7;             // kv head (XCD round-robin aligned)
  const int qidx = bid >> 3;         // 0..127
  const int qt16 = (qidx < 64) ? (2 * qidx) : (2 * (127 - qidx) + 1);  // balance
  const int h = g * 4 + wid;         // q head
  const int qrow0 = qt16 * 16;
  const int ntiles = (qrow0 + 47) >> 5;
  const int lr = lane & 15;
  const int lg = lane >> 4;

  // Q fragments: lane-linear 16B loads
  half8 qf[4];
  {
    const _Float16* qp = Qt + ((long)(h * 128 + qt16) * 4) * 512 + lane * 8;
#pragma unroll
    for (int t = 0; t < 4; t++) qf[t] = *(const half8*)(qp + t * 512);
  }

  const _Float16* kgb = Kt + (long)g * 128 * 2048 + lane * 8;  // + tile*4096 + chunk*512
  const _Float16* vgb = Vt + (long)g * 64 * 4096 + lane * 8;

  // stage tile 0: wave w stages K chunks {2w,2w+1} and V chunks {2w,2w+1}
  {
    const _Float16* ks = kgb;
    const _Float16* vs = vgb;
    async16(&Klds[0][(2 * wid) * 512],     ks + (2 * wid) * 512);
    async16(&Klds[0][(2 * wid + 1) * 512], ks + (2 * wid + 1) * 512);
    async16(&Vlds[0][(2 * wid) * 512],     vs + (2 * wid) * 512);
    async16(&Vlds[0][(2 * wid + 1) * 512], vs + (2 * wid + 1) * 512);
  }
  __syncthreads();

  f32x4 oacc[8] = {};
  float mrow[4] = {-1e30f, -1e30f, -1e30f, -1e30f};
  float lsum[4] = {0.f, 0.f, 0.f, 0.f};

  for (int t = 0; t < ntiles; t++) {
    const int kb = t * 32;
    const int cur = t & 1;
    if (t + 1 < ntiles) {  // issue next-tile staging (overlaps this tile's compute)
      const _Float16* ks = kgb + (long)(t + 1) * 4096;
      const _Float16* vs = vgb + (long)(t + 1) * 4096;
      async16(&Klds[cur ^ 1][(2 * wid) * 512],     ks + (2 * wid) * 512);
      async16(&Klds[cur ^ 1][(2 * wid + 1) * 512], ks + (2 * wid + 1) * 512);
      async16(&Vlds[cur ^ 1][(2 * wid) * 512],     vs + (2 * wid) * 512);
      async16(&Vlds[cur ^ 1][(2 * wid + 1) * 512], vs + (2 * wid + 1) * 512);
    }

    // fragment reads: lane-linear (conflict-free)
    half8 kf[8];
#pragma unroll
    for (int c = 0; c < 8; c++)
      kf[c] = *(const half8*)&Klds[cur][c * 512 + lane * 8];
    half8 vf[8];
#pragma unroll
    for (int dt = 0; dt < 8; dt++)
      vf[dt] = *(const half8*)&Vlds[cur][dt * 512 + lane * 8];

    f32x4 sacc[2] = {};
#pragma unroll
    for (int s = 0; s < 2; s++)
#pragma unroll
      for (int t2 = 0; t2 < 4; t2++)
        sacc[s] = __builtin_amdgcn_mfma_f32_16x16x32_f16(qf[t2], kf[s * 4 + t2], sacc[s], 0, 0, 0);

    // scale + causal mask + lane-local max (deferred-max)
    float mx[4];
    bool grow = false;
#pragma unroll
    for (int i = 0; i < 4; i++) {
      int qrow = qrow0 + lg * 4 + i;
      float s0 = sacc[0][i] * SCALE_QK;
      float s1 = sacc[1][i] * SCALE_QK;
      if (kb + lr > qrow) s0 = -1e30f;
      if (kb + 16 + lr > qrow) s1 = -1e30f;
      sacc[0][i] = s0; sacc[1][i] = s1;
      mx[i] = fmaxf(s0, s1);
      grow |= (mx[i] > mrow[i] + 4.0f);
    }
    if (__any((int)grow)) {  // slow path: true row-max reduce + rescale
#pragma unroll
      for (int i = 0; i < 4; i++) {
        float m = mx[i];
        m = fmaxf(m, __shfl_xor(m, 1));
        m = fmaxf(m, __shfl_xor(m, 2));
        m = fmaxf(m, __shfl_xor(m, 4));
        m = fmaxf(m, __shfl_xor(m, 8));
        float mn = fmaxf(mrow[i], m);
        float scl = __expf(mrow[i] - mn);
        mrow[i] = mn;
        lsum[i] *= scl;
#pragma unroll
        for (int dt = 0; dt < 8; dt++) oacc[dt][i] *= scl;
      }
    }
    float p[2][4];
#pragma unroll
    for (int i = 0; i < 4; i++) {
      p[0][i] = __expf(sacc[0][i] - mrow[i]);
      p[1][i] = __expf(sacc[1][i] - mrow[i]);
      lsum[i] += p[0][i] + p[1][i];
    }

    // transpose P (D-layout -> A-layout) through per-wave LDS
#pragma unroll
    for (int sub = 0; sub < 2; sub++)
#pragma unroll
      for (int i = 0; i < 4; i++)
        P_lds[wid][(lg * 4 + i) * 32 + sub * 16 + lr] = (_Float16)p[sub][i];
    half8 pa = *(const half8*)&P_lds[wid][lr * 32 + lg * 8];

    // O += P @ V
#pragma unroll
    for (int dt = 0; dt < 8; dt++)
      oacc[dt] = __builtin_amdgcn_mfma_f32_16x16x32_f16(pa, vf[dt], oacc[dt], 0, 0, 0);

    __syncthreads();  // vmcnt(0): next-tile staging done; barrier: cur consumed
  }

  // final row-sum reduce, normalize, store
#pragma unroll
  for (int i = 0; i < 4; i++) {
    float t2 = lsum[i];
    t2 += __shfl_xor(t2, 1);
    t2 += __shfl_xor(t2, 2);
    t2 += __shfl_xor(t2, 4);
    t2 += __shfl_xor(t2, 8);
    lsum[i] = t2;
  }
#pragma unroll
  for (int dt = 0; dt < 8; dt++) {
#pragma unroll
    for (int i = 0; i < 4; i++) {
      float o = oacc[dt][i] / lsum[i];
      O[(long)(qrow0 + lg * 4 + i) * HID_DIM + h * HEAD_DIM + dt * 16 + lr] = (_Float16)o;
    }
  }
}

extern "C" void kernel_launch(void* const* d_in, const int* in_sizes, int n_in,
                              void* d_out, int out_size, void* d_ws, size_t ws_size,
                              hipStream_t stream) {
  const float* x    = (const float*)d_in[0];
  const float* cosb = (const float*)d_in[1];
  const float* sinb = (const float*)d_in[2];
  // d_in[3] = attn_mask: pure causal, implemented in-kernel
  const float* wq = (const float*)d_in[4];
  const float* wk = (const float*)d_in[5];
  const float* wv = (const float*)d_in[6];
  const float* wo = (const float*)d_in[7];
  float* out = (float*)d_out;

  char* ws = (char*)d_ws;
  _Float16* Xh     = (_Float16*)(ws);                       // 0..16M  (X f16; later Qtiled)
  _Float16* Qtiled = Xh;
  _Float16* Qb     = (_Float16*)(ws + (size_t)(16 << 20));  // 16..32M (Q linear; later Oattn)
  _Float16* Oattn  = Qb;
  _Float16* Kbuf   = (_Float16*)(ws + (size_t)(32 << 20));  // 32..36M (K linear)
  _Float16* Vt2    = (_Float16*)(ws + (size_t)(36 << 20));  // 36..40M (V tiled)
  _Float16* Wt1    = (_Float16*)(ws + (size_t)(40 << 20));  // 40..72M (weightsT)
  _Float16* Kt     = (_Float16*)(ws + (size_t)(72 << 20));  // 72..76M (K tiled)
  // total 76 MiB

  dim3 b256(256);

  // X -> f16
  conv_f32_f16<<<dim3(S_LEN * HID_DIM / 4 / 256), b256, 0, stream>>>(x, Xh, S_LEN * HID_DIM / 4);

  // Q = X @ Wq (linear)
  transpose_f32_f16<<<dim3(4096 / 32, 4096 / 32), dim3(32, 8), 0, stream>>>(wq, Wt1, 4096, 4096);
  gemm_kernel<4096, 0><<<dim3(4096 / 128, S_LEN / 128), b256, 0, stream>>>(Xh, Wt1, Qb, nullptr);

  // K (linear) | V (frag-tiled) merged GEMM
  transpose_f32_f16<<<dim3(1024 / 32, 4096 / 32), dim3(32, 8), 0, stream>>>(wk, Wt1, 4096, 1024);
  transpose_f32_f16<<<dim3(1024 / 32, 4096 / 32), dim3(32, 8), 0, stream>>>(wv, Wt1 + (size_t)1024 * 4096, 4096, 1024);
  gemm_kernel<2048, 3><<<dim3(2048 / 128, S_LEN / 128), b256, 0, stream>>>(Xh, Wt1, Kbuf, Vt2);

  // RoPE + retile (Q: Qb -> Qtiled, K: Kbuf -> Kt)
  rope_tile_kernel<N_HEADS><<<dim3(S_LEN * N_HEADS * 16 / 256), b256, 0, stream>>>(Qb, Qtiled, cosb, sinb);
  rope_tile_kernel<N_KV><<<dim3(S_LEN * N_KV * 16 / 256), b256, 0, stream>>>(Kbuf, Kt, cosb, sinb);

  // fused causal GQA attention -> Oattn
  attn_kernel<<<dim3(1024), b256, 0, stream>>>(Qtiled, Kt, Vt2, Oattn);

  // out = Oattn @ Wo (f32 out)
  transpose_f32_f16<<<dim3(4096 / 32, 4096 / 32), dim3(32, 8), 0, stream>>>(wo, Wt1, 4096, 4096);
  gemm_kernel<4096, 2><<<dim3(4096 / 128, S_LEN / 128), b256, 0, stream>>>(Oattn, Wt1, out, nullptr);
}

// Round 5
// 327.706 us; speedup vs baseline: 2.5573x; 1.2079x over previous
//
#include <hip/hip_runtime.h>
#include <hip/hip_bf16.h>
#include <hip/hip_fp16.h>

typedef _Float16 half8 __attribute__((ext_vector_type(8)));
typedef _Float16 half4 __attribute__((ext_vector_type(4)));
typedef float f32x4 __attribute__((ext_vector_type(4)));
typedef unsigned int u32;

#define S_LEN 2048
#define HID_DIM 4096
#define N_HEADS 32
#define N_KV 8
#define HEAD_DIM 128
#define SCALE_QK 0.08838834764831845f

// ---------- async global->LDS (16B per lane, wave-uniform LDS base) ----------
__device__ __forceinline__ void async16(void* lds, const void* gptr) {
  __builtin_amdgcn_global_load_lds(
      (const __attribute__((address_space(1))) u32*)gptr,
      (__attribute__((address_space(3))) u32*)lds, 16, 0, 0);
}

// ---------- f32 -> f16 convert (vectorized) ----------
__global__ void conv_f32_f16(const float* __restrict__ src, _Float16* __restrict__ dst, int n4) {
  int i = blockIdx.x * 256 + threadIdx.x;
  if (i < n4) {
    float4 v = ((const float4*)src)[i];
    half4 h;
    h[0] = (_Float16)v.x; h[1] = (_Float16)v.y; h[2] = (_Float16)v.z; h[3] = (_Float16)v.w;
    ((half4*)dst)[i] = h;
  }
}

// ---------- transpose f32 [R][C] -> f16 [C][R], 64(R)x32(C) tiles, 128B writes ----------
__global__ void transpose_f32_f16(const float* __restrict__ src, _Float16* __restrict__ dst,
                                  int R, int C) {
  __shared__ _Float16 tile[64][33];
  int bx = blockIdx.x;  // over C/32
  int by = blockIdx.y;  // over R/64
  int x = threadIdx.x, y = threadIdx.y;  // (32,8)
#pragma unroll
  for (int k = 0; k < 8; k++)
    tile[y + 8 * k][x] = (_Float16)src[(long)(by * 64 + y + 8 * k) * C + bx * 32 + x];
  __syncthreads();
  int tid = y * 32 + x;
  int r = tid & 63;
  int cb = tid >> 6;
#pragma unroll
  for (int w = 0; w < 8; w++) {
    int c = w * 4 + cb;
    dst[(long)(bx * 32 + c) * R + by * 64 + r] = tile[r][c];
  }
}

// ---------- RoPE in place on frag-tiled [h][s16][d/32][slot] layout ----------
// element (h,s,d): chunk=(h*128+s/16)*4+d/32, off=((d>>3)&3)*128+(s&15)*8+(d&7)
// cos[d] == cos[d%64] (emb = concat[freqs,freqs]) so one table read serves both halves.
template <int NHEADS>
__global__ void rope_tiled(_Float16* __restrict__ t, const float* __restrict__ cosb,
                           const float* __restrict__ sinb) {
  int idx = blockIdx.x * 256 + threadIdx.x;  // NHEADS * 2048 * 8
  int slo = idx & 15;
  int d8 = (idx >> 4) & 7;
  int h = (idx >> 7) % NHEADS;
  int s16 = idx / (128 * NHEADS);
  int s = s16 * 16 + slo;
  int d0 = d8 * 8;
  long c0 = (long)(h * 128 + s16) * 4;
  long base = (c0 + (d0 >> 5)) * 512 + ((d0 >> 3) & 3) * 128 + slo * 8;
  half8 a = *(half8*)(t + base);
  half8 b = *(half8*)(t + base + 1024);  // d0+64 -> chunk+2
  const float* cp = cosb + s * 128 + d0;
  const float* sp = sinb + s * 128 + d0;
  half8 olo, ohi;
#pragma unroll
  for (int j = 0; j < 8; j++) {
    float c = cp[j], sn = sp[j];
    float av = (float)a[j], bv = (float)b[j];
    olo[j] = (_Float16)(av * c - bv * sn);
    ohi[j] = (_Float16)(bv * c + av * sn);
  }
  *(half8*)(t + base) = olo;
  *(half8*)(t + base + 1024) = ohi;
}

// ---------- merged QKV GEMM: [2048][4096] @ [6144][4096]^T, BK=64, swizzled LDS ----------
// cols [0,4096): Q frag-tiled pre-rope; [4096,5120): K frag-tiled pre-rope;
// [5120,6144): V PV-fragment layout.
__global__ __launch_bounds__(256, 3) void gemm_qkv(
    const _Float16* __restrict__ A, const _Float16* __restrict__ BtQ,
    const _Float16* __restrict__ BtKV, _Float16* __restrict__ Qt,
    _Float16* __restrict__ Kt, _Float16* __restrict__ Vt) {
  __shared__ _Float16 As[128 * 64];
  __shared__ _Float16 Bs[128 * 64];
  const int K = 4096;
  const int tid = threadIdx.x, lane = tid & 63, wid = tid >> 6;
  const int row0 = blockIdx.y * 128;
  const int col0 = blockIdx.x * 128;
  const int wm = wid >> 1, wn = wid & 1;
  const int lr = lane & 15, lg = lane >> 4;

  const _Float16* bbase = (col0 < 4096) ? (BtQ + (long)col0 * K)
                                        : (BtKV + (long)(col0 - 4096) * K);
  // staging: LDS dest is linear; global source column pre-swizzled (involution)
  const int scol = ((lane & 7) ^ ((lane >> 3) & 7)) * 8;
  const _Float16* aptr = A + (long)(row0 + wid * 32 + (lane >> 3)) * K + scol;
  const _Float16* bptr = bbase + (long)(wid * 32 + (lane >> 3)) * K + scol;
  _Float16* alds = As + (wid * 4) * 512;
  _Float16* blds = Bs + (wid * 4) * 512;

  f32x4 acc[4][4] = {};
  for (int k0 = 0; k0 < K; k0 += 64) {
#pragma unroll
    for (int j = 0; j < 4; j++) {
      async16(alds + j * 512, aptr + k0 + (long)j * 8 * K);
      async16(blds + j * 512, bptr + k0 + (long)j * 8 * K);
    }
    __syncthreads();
    half8 a[2][4], b[2][4];
#pragma unroll
    for (int kk = 0; kk < 2; kk++)
#pragma unroll
      for (int mf = 0; mf < 4; mf++) {
        a[kk][mf] = *(const half8*)&As[(wm * 64 + mf * 16 + lr) * 64 +
                                       (((kk * 4 + lg) ^ (lr & 7)) * 8)];
        b[kk][mf] = *(const half8*)&Bs[(wn * 64 + mf * 16 + lr) * 64 +
                                       (((kk * 4 + lg) ^ (lr & 7)) * 8)];
      }
#pragma unroll
    for (int kk = 0; kk < 2; kk++)
#pragma unroll
      for (int mf = 0; mf < 4; mf++)
#pragma unroll
        for (int nf = 0; nf < 4; nf++)
          acc[mf][nf] =
              __builtin_amdgcn_mfma_f32_16x16x32_f16(a[kk][mf], b[kk][nf], acc[mf][nf], 0, 0, 0);
    __syncthreads();
  }

  // epilogue: C/D frag mapping col = lane&15, row = (lane>>4)*4 + i
#pragma unroll
  for (int mf = 0; mf < 4; mf++) {
#pragma unroll
    for (int nf = 0; nf < 4; nf++) {
      int rbase = row0 + wm * 64 + mf * 16 + lg * 4;  // s
      int col = col0 + wn * 64 + nf * 16 + lr;
      if (col0 < 4096) {  // Q frag-tiled (pre-rope)
        int h = col >> 7, d = col & 127;
        long off = ((long)((h * 128 + (rbase >> 4)) * 4 + (d >> 5))) * 512 +
                   ((d >> 3) & 3) * 128 + (rbase & 15) * 8 + (d & 7);
#pragma unroll
        for (int i = 0; i < 4; i++) Qt[off + i * 8] = (_Float16)acc[mf][nf][i];
      } else if (col0 < 5120) {  // K frag-tiled (pre-rope)
        int gc = col - 4096;
        int g = gc >> 7, d = gc & 127;
        long off = ((long)((g * 128 + (rbase >> 4)) * 4 + (d >> 5))) * 512 +
                   ((d >> 3) & 3) * 128 + (rbase & 15) * 8 + (d & 7);
#pragma unroll
        for (int i = 0; i < 4; i++) Kt[off + i * 8] = (_Float16)acc[mf][nf][i];
      } else {  // V PV-fragment layout
        int gc = col - 5120;
        int gq = gc >> 7, d = gc & 127;
        int dt = d >> 4, lrr = d & 15;
        int kvb = rbase >> 5, lgv = (rbase >> 3) & 3, j = rbase & 7;
        half4 v;
#pragma unroll
        for (int i = 0; i < 4; i++) v[i] = (_Float16)acc[mf][nf][i];
        long off = ((long)(gq * 64 + kvb) * 8 + dt) * 512 + (lgv * 16 + lrr) * 8 + j;
        *(half4*)&Vt[off] = v;
      }
    }
  }
}

// ---------- O-projection GEMM: [2048][4096] f16 @ [4096][4096]^T -> f32 out ----------
__global__ __launch_bounds__(256, 3) void gemm_out(
    const _Float16* __restrict__ A, const _Float16* __restrict__ Bt,
    float* __restrict__ C) {
  __shared__ _Float16 As[128 * 64];
  __shared__ _Float16 Bs[128 * 64];
  const int K = 4096;
  const int tid = threadIdx.x, lane = tid & 63, wid = tid >> 6;
  const int row0 = blockIdx.y * 128;
  const int col0 = blockIdx.x * 128;
  const int wm = wid >> 1, wn = wid & 1;
  const int lr = lane & 15, lg = lane >> 4;

  const int scol = ((lane & 7) ^ ((lane >> 3) & 7)) * 8;
  const _Float16* aptr = A + (long)(row0 + wid * 32 + (lane >> 3)) * K + scol;
  const _Float16* bptr = Bt + (long)(col0 + wid * 32 + (lane >> 3)) * K + scol;
  _Float16* alds = As + (wid * 4) * 512;
  _Float16* blds = Bs + (wid * 4) * 512;

  f32x4 acc[4][4] = {};
  for (int k0 = 0; k0 < K; k0 += 64) {
#pragma unroll
    for (int j = 0; j < 4; j++) {
      async16(alds + j * 512, aptr + k0 + (long)j * 8 * K);
      async16(blds + j * 512, bptr + k0 + (long)j * 8 * K);
    }
    __syncthreads();
    half8 a[2][4], b[2][4];
#pragma unroll
    for (int kk = 0; kk < 2; kk++)
#pragma unroll
      for (int mf = 0; mf < 4; mf++) {
        a[kk][mf] = *(const half8*)&As[(wm * 64 + mf * 16 + lr) * 64 +
                                       (((kk * 4 + lg) ^ (lr & 7)) * 8)];
        b[kk][mf] = *(const half8*)&Bs[(wn * 64 + mf * 16 + lr) * 64 +
                                       (((kk * 4 + lg) ^ (lr & 7)) * 8)];
      }
#pragma unroll
    for (int kk = 0; kk < 2; kk++)
#pragma unroll
      for (int mf = 0; mf < 4; mf++)
#pragma unroll
        for (int nf = 0; nf < 4; nf++)
          acc[mf][nf] =
              __builtin_amdgcn_mfma_f32_16x16x32_f16(a[kk][mf], b[kk][nf], acc[mf][nf], 0, 0, 0);
    __syncthreads();
  }
#pragma unroll
  for (int mf = 0; mf < 4; mf++)
#pragma unroll
    for (int nf = 0; nf < 4; nf++) {
      int rbase = row0 + wm * 64 + mf * 16 + lg * 4;
      int col = col0 + wn * 64 + nf * 16 + lr;
#pragma unroll
      for (int i = 0; i < 4; i++)
        C[(long)(rbase + i) * 4096 + col] = acc[mf][nf][i];
    }
}

// ---------- fused causal GQA attention, LDS-shared K/V (unchanged from R4) ----------
__global__ __launch_bounds__(256, 3) void attn_kernel(
    const _Float16* __restrict__ Qt, const _Float16* __restrict__ Kt,
    const _Float16* __restrict__ Vt, _Float16* __restrict__ O) {
  __shared__ _Float16 Klds[2][4096];
  __shared__ _Float16 Vlds[2][4096];
  __shared__ _Float16 P_lds[4][512];
  const int tid = threadIdx.x;
  const int lane = tid & 63;
  const int wid = tid >> 6;
  const int bid = blockIdx.x;  // 1024
  const int g = bid & 7;
  const int qidx = bid >> 3;
  const int qt16 = (qidx < 64) ? (2 * qidx) : (2 * (127 - qidx) + 1);
  const int h = g * 4 + wid;
  const int qrow0 = qt16 * 16;
  const int ntiles = (qrow0 + 47) >> 5;
  const int lr = lane & 15;
  const int lg = lane >> 4;

  half8 qf[4];
  {
    const _Float16* qp = Qt + ((long)(h * 128 + qt16) * 4) * 512 + lane * 8;
#pragma unroll
    for (int t = 0; t < 4; t++) qf[t] = *(const half8*)(qp + t * 512);
  }

  const _Float16* kgb = Kt + (long)g * 128 * 2048 + lane * 8;
  const _Float16* vgb = Vt + (long)g * 64 * 4096 + lane * 8;

  {
    async16(&Klds[0][(2 * wid) * 512], kgb + (2 * wid) * 512);
    async16(&Klds[0][(2 * wid + 1) * 512], kgb + (2 * wid + 1) * 512);
    async16(&Vlds[0][(2 * wid) * 512], vgb + (2 * wid) * 512);
    async16(&Vlds[0][(2 * wid + 1) * 512], vgb + (2 * wid + 1) * 512);
  }
  __syncthreads();

  f32x4 oacc[8] = {};
  float mrow[4] = {-1e30f, -1e30f, -1e30f, -1e30f};
  float lsum[4] = {0.f, 0.f, 0.f, 0.f};

  for (int t = 0; t < ntiles; t++) {
    const int kb = t * 32;
    const int cur = t & 1;
    if (t + 1 < ntiles) {
      const _Float16* ks = kgb + (long)(t + 1) * 4096;
      const _Float16* vs = vgb + (long)(t + 1) * 4096;
      async16(&Klds[cur ^ 1][(2 * wid) * 512], ks + (2 * wid) * 512);
      async16(&Klds[cur ^ 1][(2 * wid + 1) * 512], ks + (2 * wid + 1) * 512);
      async16(&Vlds[cur ^ 1][(2 * wid) * 512], vs + (2 * wid) * 512);
      async16(&Vlds[cur ^ 1][(2 * wid + 1) * 512], vs + (2 * wid + 1) * 512);
    }

    half8 kf[8];
#pragma unroll
    for (int c = 0; c < 8; c++)
      kf[c] = *(const half8*)&Klds[cur][c * 512 + lane * 8];
    half8 vf[8];
#pragma unroll
    for (int dt = 0; dt < 8; dt++)
      vf[dt] = *(const half8*)&Vlds[cur][dt * 512 + lane * 8];

    f32x4 sacc[2] = {};
#pragma unroll
    for (int s = 0; s < 2; s++)
#pragma unroll
      for (int t2 = 0; t2 < 4; t2++)
        sacc[s] = __builtin_amdgcn_mfma_f32_16x16x32_f16(qf[t2], kf[s * 4 + t2], sacc[s], 0, 0, 0);

    float mx[4];
    bool grow = false;
#pragma unroll
    for (int i = 0; i < 4; i++) {
      int qrow = qrow0 + lg * 4 + i;
      float s0 = sacc[0][i] * SCALE_QK;
      float s1 = sacc[1][i] * SCALE_QK;
      if (kb + lr > qrow) s0 = -1e30f;
      if (kb + 16 + lr > qrow) s1 = -1e30f;
      sacc[0][i] = s0; sacc[1][i] = s1;
      mx[i] = fmaxf(s0, s1);
      grow |= (mx[i] > mrow[i] + 4.0f);
    }
    if (__any((int)grow)) {
#pragma unroll
      for (int i = 0; i < 4; i++) {
        float m = mx[i];
        m = fmaxf(m, __shfl_xor(m, 1));
        m = fmaxf(m, __shfl_xor(m, 2));
        m = fmaxf(m, __shfl_xor(m, 4));
        m = fmaxf(m, __shfl_xor(m, 8));
        float mn = fmaxf(mrow[i], m);
        float scl = __expf(mrow[i] - mn);
        mrow[i] = mn;
        lsum[i] *= scl;
#pragma unroll
        for (int dt = 0; dt < 8; dt++) oacc[dt][i] *= scl;
      }
    }
    float p[2][4];
#pragma unroll
    for (int i = 0; i < 4; i++) {
      p[0][i] = __expf(sacc[0][i] - mrow[i]);
      p[1][i] = __expf(sacc[1][i] - mrow[i]);
      lsum[i] += p[0][i] + p[1][i];
    }

#pragma unroll
    for (int sub = 0; sub < 2; sub++)
#pragma unroll
      for (int i = 0; i < 4; i++)
        P_lds[wid][(lg * 4 + i) * 32 + sub * 16 + lr] = (_Float16)p[sub][i];
    half8 pa = *(const half8*)&P_lds[wid][lr * 32 + lg * 8];

#pragma unroll
    for (int dt = 0; dt < 8; dt++)
      oacc[dt] = __builtin_amdgcn_mfma_f32_16x16x32_f16(pa, vf[dt], oacc[dt], 0, 0, 0);

    __syncthreads();
  }

#pragma unroll
  for (int i = 0; i < 4; i++) {
    float t2 = lsum[i];
    t2 += __shfl_xor(t2, 1);
    t2 += __shfl_xor(t2, 2);
    t2 += __shfl_xor(t2, 4);
    t2 += __shfl_xor(t2, 8);
    lsum[i] = t2;
  }
#pragma unroll
  for (int dt = 0; dt < 8; dt++) {
#pragma unroll
    for (int i = 0; i < 4; i++) {
      float o = oacc[dt][i] / lsum[i];
      O[(long)(qrow0 + lg * 4 + i) * HID_DIM + h * HEAD_DIM + dt * 16 + lr] = (_Float16)o;
    }
  }
}

extern "C" void kernel_launch(void* const* d_in, const int* in_sizes, int n_in,
                              void* d_out, int out_size, void* d_ws, size_t ws_size,
                              hipStream_t stream) {
  const float* x    = (const float*)d_in[0];
  const float* cosb = (const float*)d_in[1];
  const float* sinb = (const float*)d_in[2];
  // d_in[3] = attn_mask: pure causal, implemented in-kernel
  const float* wq = (const float*)d_in[4];
  const float* wk = (const float*)d_in[5];
  const float* wv = (const float*)d_in[6];
  const float* wo = (const float*)d_in[7];
  float* out = (float*)d_out;

  char* ws = (char*)d_ws;
  _Float16* Xh    = (_Float16*)(ws);                        // [0,16M): X f16; later Oattn
  _Float16* Oattn = Xh;
  _Float16* Qt    = (_Float16*)(ws + (size_t)(16 << 20));   // [16,32M): Q frag-tiled
  _Float16* Kt    = (_Float16*)(ws + (size_t)(32 << 20));   // [32,36M): K frag-tiled
  _Float16* Vt    = (_Float16*)(ws + (size_t)(36 << 20));   // [36,40M): V PV-tiled
  _Float16* WqT   = (_Float16*)(ws + (size_t)(40 << 20));   // [40,72M): wq^T, later wo^T
  _Float16* WoT   = WqT;
  _Float16* WkvT  = (_Float16*)d_out;                       // 16MB scratch in d_out
  // peak ws usage: 72 MiB

  dim3 b256(256);
  dim3 tb(32, 8);

  // X -> f16
  conv_f32_f16<<<dim3(S_LEN * HID_DIM / 4 / 256), b256, 0, stream>>>(x, Xh, S_LEN * HID_DIM / 4);

  // weight transposes: wq^T -> ws; wk^T|wv^T -> d_out scratch
  transpose_f32_f16<<<dim3(4096 / 32, 4096 / 64), tb, 0, stream>>>(wq, WqT, 4096, 4096);
  transpose_f32_f16<<<dim3(1024 / 32, 4096 / 64), tb, 0, stream>>>(wk, WkvT, 4096, 1024);
  transpose_f32_f16<<<dim3(1024 / 32, 4096 / 64), tb, 0, stream>>>(wv, WkvT + (size_t)1024 * 4096, 4096, 1024);

  // merged QKV projection (N=6144, 768 blocks = 3/CU)
  gemm_qkv<<<dim3(6144 / 128, S_LEN / 128), b256, 0, stream>>>(Xh, WqT, WkvT, Qt, Kt, Vt);

  // RoPE in place on tiled Q/K
  rope_tiled<N_HEADS><<<dim3(N_HEADS * 16384 / 256), b256, 0, stream>>>(Qt, cosb, sinb);
  rope_tiled<N_KV><<<dim3(N_KV * 16384 / 256), b256, 0, stream>>>(Kt, cosb, sinb);

  // fused causal GQA attention -> Oattn (reuses Xh region)
  attn_kernel<<<dim3(1024), b256, 0, stream>>>(Qt, Kt, Vt, Oattn);

  // out = Oattn @ Wo (f32)
  transpose_f32_f16<<<dim3(4096 / 32, 4096 / 64), tb, 0, stream>>>(wo, WoT, 4096, 4096);
  gemm_out<<<dim3(4096 / 128, S_LEN / 128), b256, 0, stream>>>(Oattn, WoT, out);
}